// Round 1
// baseline (540.486 us; speedup 1.0000x reference)
//
#include <hip/hip_runtime.h>

#define BB 32
#define NN_ 128
#define NIN 64
#define MH 256
#define MO 64
#define NH 256
#define NO 64
#define EDGES 16256

// ws layout (floats):
//   ps_t: [B][MH][N]   offset 0         size 32*256*128 = 1048576
//   pr:   [B][N][MH]   offset 1048576   size 1048576
//   w2t:  [MH][MO]     offset 2097152   size 16384
//   agg:  [B][N][MO]   offset 2113536   size 262144
// total 2375680 floats = 9.5 MB

// ---------------------------------------------------------------------------
// Kernel 1: per-node fc1 partials (sender part Ps, receiver part Pr incl b1)
//           + transpose of msg_fc2_w into [k][j] layout.
// blocks 0..1023: 4 nodes each (b = blk>>5, nodes (blk&31)*4 ..+3), 256 thr = h
// blocks 1024..1087: W2 transpose (16384 elements)
// ---------------------------------------------------------------------------
__global__ __launch_bounds__(256) void prep_kernel(
    const float* __restrict__ x, const float* __restrict__ W1,
    const float* __restrict__ b1, const float* __restrict__ W2,
    float* __restrict__ ps_t, float* __restrict__ pr, float* __restrict__ w2t)
{
    int blk = blockIdx.x;
    int t = threadIdx.x;
    if (blk < 1024) {
        int b  = blk >> 5;
        int n0 = (blk & 31) << 2;
        __shared__ float xL[4][64];
        xL[t >> 6][t & 63] = x[((b * NN_) + n0 + (t >> 6)) * NIN + (t & 63)];
        __syncthreads();

        const float4* w1r = (const float4*)(W1 + t * (2 * NIN)); // row t: 32 float4
        float ps[4] = {0.f, 0.f, 0.f, 0.f};
        float prv[4];
        float bv = b1[t];
        #pragma unroll
        for (int nn = 0; nn < 4; ++nn) prv[nn] = bv;

        #pragma unroll
        for (int f4 = 0; f4 < 16; ++f4) {          // sender half: cols 0..63
            float4 w = w1r[f4];
            #pragma unroll
            for (int nn = 0; nn < 4; ++nn) {
                ps[nn] += w.x * xL[nn][4*f4+0] + w.y * xL[nn][4*f4+1]
                        + w.z * xL[nn][4*f4+2] + w.w * xL[nn][4*f4+3];
            }
        }
        #pragma unroll
        for (int f4 = 0; f4 < 16; ++f4) {          // receiver half: cols 64..127
            float4 w = w1r[16 + f4];
            #pragma unroll
            for (int nn = 0; nn < 4; ++nn) {
                prv[nn] += w.x * xL[nn][4*f4+0] + w.y * xL[nn][4*f4+1]
                         + w.z * xL[nn][4*f4+2] + w.w * xL[nn][4*f4+3];
            }
        }
        #pragma unroll
        for (int nn = 0; nn < 4; ++nn) {
            pr[((b * NN_) + n0 + nn) * MH + t] = prv[nn];        // [b][n][k]
            ps_t[(b * MH + t) * NN_ + n0 + nn] = ps[nn];         // [b][k][n]
        }
    } else {
        int i = ((blk - 1024) << 8) + t;   // 0..16383
        int k = i >> 6, j = i & 63;
        w2t[i] = W2[j * MH + k];           // w2t[k][j] = W2[j][k]
    }
}

// ---------------------------------------------------------------------------
// Kernel 2: edge MLP fc2 + rt-weighted segment-sum into agg.
// One block per (b, r). 128 threads; thread t = sender slot t (t==127 pad).
// Lane holds 64 fp32 accumulators; per k: h1 = relu(Ps[sender,k]+Pr[r,k])
// (coalesced vector load + broadcast), then 64 FMAs against wave-uniform
// float4 broadcast loads of w2t[k][*] (1 L1 line each).
// ---------------------------------------------------------------------------
__global__ __launch_bounds__(128) void edge_kernel(
    const float* __restrict__ rt, const float* __restrict__ b2,
    const float* __restrict__ ps_t, const float* __restrict__ pr,
    const float* __restrict__ w2t, float* __restrict__ agg)
{
    int blk = blockIdx.x;
    int b = blk >> 7;
    int r = blk & 127;
    int t = threadIdx.x;            // sender slot 0..127
    bool valid = (t < 127);
    int sender = t + (t >= r ? 1 : 0);
    if (!valid) sender = 0;         // clamp pad lane; zeroed via rtw
    float rtw = 0.f;
    if (valid) {
        const float* p = rt + ((size_t)b * EDGES + (size_t)r * 127 + t) * 2;
        rtw = p[0] + p[1];
    }
    const float*  psb = ps_t + b * (MH * NN_);
    const float*  prb = pr + (b * NN_ + r) * MH;
    const float4* w2  = (const float4*)w2t;

    float acc[64];
    #pragma unroll
    for (int j = 0; j < 64; ++j) acc[j] = 0.f;

    for (int k = 0; k < MH; ++k) {
        float h1 = psb[k * NN_ + sender] + prb[k];
        h1 = fmaxf(h1, 0.f);
        const float4* wr = w2 + k * 16;
        #pragma unroll
        for (int jj = 0; jj < 16; ++jj) {
            float4 w = wr[jj];
            acc[4*jj+0] = fmaf(h1, w.x, acc[4*jj+0]);
            acc[4*jj+1] = fmaf(h1, w.y, acc[4*jj+1]);
            acc[4*jj+2] = fmaf(h1, w.z, acc[4*jj+2]);
            acc[4*jj+3] = fmaf(h1, w.w, acc[4*jj+3]);
        }
    }

    // epilogue: msg = relu(acc + b2) * rtw ; column-reduce over 128 sender rows
    __shared__ float red[128 * 65];   // +1 pad: bank (t + j) % 32, conflict-free
    const float4* b24 = (const float4*)b2;
    #pragma unroll
    for (int jj = 0; jj < 16; ++jj) {
        float4 bb = b24[jj];
        red[t * 65 + 4*jj+0] = fmaxf(acc[4*jj+0] + bb.x, 0.f) * rtw;
        red[t * 65 + 4*jj+1] = fmaxf(acc[4*jj+1] + bb.y, 0.f) * rtw;
        red[t * 65 + 4*jj+2] = fmaxf(acc[4*jj+2] + bb.z, 0.f) * rtw;
        red[t * 65 + 4*jj+3] = fmaxf(acc[4*jj+3] + bb.w, 0.f) * rtw;
    }
    __syncthreads();
    if (t < 64) {
        float s = 0.f;
        #pragma unroll 8
        for (int row = 0; row < 128; ++row) s += red[row * 65 + t];
        agg[(b * NN_ + r) * MO + t] = s;
    }
}

// ---------------------------------------------------------------------------
// Kernel 3: node MLP (64 -> 256 -> 256 -> 64). 8 nodes per block to amortize
// O2 (256 KB) reads. 256 threads.
// ---------------------------------------------------------------------------
__global__ __launch_bounds__(256) void node_kernel(
    const float* __restrict__ agg, const float* __restrict__ O1,
    const float* __restrict__ b1o, const float* __restrict__ O2,
    const float* __restrict__ b2o, const float* __restrict__ O3,
    const float* __restrict__ b3o, float* __restrict__ out)
{
    int t  = threadIdx.x;
    int b  = blockIdx.x >> 4;
    int n0 = (blockIdx.x & 15) << 3;
    __shared__ float aggL[8][64];
    __shared__ float h1L[8][256];
    __shared__ float h2L[8][256];

    for (int i = t; i < 512; i += 256)
        aggL[i >> 6][i & 63] = agg[((b * NN_) + n0 + (i >> 6)) * MO + (i & 63)];
    __syncthreads();

    { // fc1: thread t = hidden unit p
        const float4* row = (const float4*)(O1 + t * MO);
        float s[8];
        float bv = b1o[t];
        #pragma unroll
        for (int nn = 0; nn < 8; ++nn) s[nn] = bv;
        #pragma unroll
        for (int f4 = 0; f4 < 16; ++f4) {
            float4 w = row[f4];
            #pragma unroll
            for (int nn = 0; nn < 8; ++nn)
                s[nn] += w.x*aggL[nn][4*f4+0] + w.y*aggL[nn][4*f4+1]
                       + w.z*aggL[nn][4*f4+2] + w.w*aggL[nn][4*f4+3];
        }
        #pragma unroll
        for (int nn = 0; nn < 8; ++nn) h1L[nn][t] = fmaxf(s[nn], 0.f);
    }
    __syncthreads();

    { // fc2: thread t = hidden unit q
        const float4* row = (const float4*)(O2 + t * NH);
        float s[8];
        float bv = b2o[t];
        #pragma unroll
        for (int nn = 0; nn < 8; ++nn) s[nn] = bv;
        for (int f4 = 0; f4 < 64; ++f4) {
            float4 w = row[f4];
            #pragma unroll
            for (int nn = 0; nn < 8; ++nn)
                s[nn] += w.x*h1L[nn][4*f4+0] + w.y*h1L[nn][4*f4+1]
                       + w.z*h1L[nn][4*f4+2] + w.w*h1L[nn][4*f4+3];
        }
        #pragma unroll
        for (int nn = 0; nn < 8; ++nn) h2L[nn][t] = fmaxf(s[nn], 0.f);
    }
    __syncthreads();

    // fc3: 512 (node, out) pairs over 2 passes
    #pragma unroll
    for (int pass = 0; pass < 2; ++pass) {
        int id = pass * 256 + t;
        int nn = id >> 6;     // 0..7
        int o  = id & 63;
        const float4* row = (const float4*)(O3 + o * NH);
        float s = b3o[o];
        for (int f4 = 0; f4 < 64; ++f4) {
            float4 w = row[f4];
            s += w.x*h2L[nn][4*f4+0] + w.y*h2L[nn][4*f4+1]
               + w.z*h2L[nn][4*f4+2] + w.w*h2L[nn][4*f4+3];
        }
        out[((b * NN_) + n0 + nn) * NO + o] = s;
    }
}

// ---------------------------------------------------------------------------
extern "C" void kernel_launch(void* const* d_in, const int* in_sizes, int n_in,
                              void* d_out, int out_size, void* d_ws, size_t ws_size,
                              hipStream_t stream) {
    const float* x   = (const float*)d_in[0];
    // d_in[1] rel_rec, d_in[2] rel_send: structure is known (recv-major,
    // senders ascending skipping r) — not needed as data.
    const float* rt  = (const float*)d_in[3];
    const float* W1  = (const float*)d_in[4];
    const float* b1  = (const float*)d_in[5];
    const float* W2  = (const float*)d_in[6];
    const float* b2  = (const float*)d_in[7];
    const float* O1  = (const float*)d_in[8];
    const float* b1o = (const float*)d_in[9];
    const float* O2  = (const float*)d_in[10];
    const float* b2o = (const float*)d_in[11];
    const float* O3  = (const float*)d_in[12];
    const float* b3o = (const float*)d_in[13];

    float* ws   = (float*)d_ws;
    float* ps_t = ws;
    float* pr   = ws + 1048576;
    float* w2t  = ws + 2097152;
    float* agg  = ws + 2113536;
    float* out  = (float*)d_out;

    hipLaunchKernelGGL(prep_kernel, dim3(1088), dim3(256), 0, stream,
                       x, W1, b1, W2, ps_t, pr, w2t);
    hipLaunchKernelGGL(edge_kernel, dim3(4096), dim3(128), 0, stream,
                       rt, b2, ps_t, pr, w2t, agg);
    hipLaunchKernelGGL(node_kernel, dim3(512), dim3(256), 0, stream,
                       agg, O1, b1o, O2, b2o, O3, b3o, out);
}

// Round 2
// 298.252 us; speedup vs baseline: 1.8122x; 1.8122x over previous
//
#include <hip/hip_runtime.h>

#define BB 32
#define NN_ 128
#define NIN 64
#define MH 256
#define MO 64
#define NH 256
#define NO 64
#define EDGES 16256

typedef __attribute__((ext_vector_type(8))) short short8;   // 8 bf16 = 4 VGPRs
typedef __attribute__((ext_vector_type(4))) float f32x4;    // MFMA acc

// ws layout (floats):
//   ps:  [B][N][MH] fp32  offset 0        size 32*128*256 = 1048576
//   pr:  [B][N][MH] fp32  offset 1048576  size 1048576
//   w2b: [MO][MH]  bf16   offset 2097152  size 16384 bf16 = 8192 floats
//   agg: [B][N][MO] fp32  offset 2105344  size 262144
// total 2367488 floats = 9.47 MB

static __device__ __forceinline__ short f2bf(float f) {  // RNE float->bf16
    unsigned u = __float_as_uint(f);
    u = (u + 0x7fffu + ((u >> 16) & 1u)) >> 16;
    return (short)u;
}

// ---------------------------------------------------------------------------
// Kernel 1: per-node fc1 partials Ps (sender half), Pr (receiver half + b1),
// both in [b][node][k] layout, + bf16 cast of msg_fc2_w ([MO][MH] row-major).
// ---------------------------------------------------------------------------
__global__ __launch_bounds__(256) void prep_kernel(
    const float* __restrict__ x, const float* __restrict__ W1,
    const float* __restrict__ b1, const float* __restrict__ W2,
    float* __restrict__ ps, float* __restrict__ pr, short* __restrict__ w2b)
{
    int blk = blockIdx.x;
    int t = threadIdx.x;
    if (blk < 1024) {
        int b  = blk >> 5;
        int n0 = (blk & 31) << 2;
        __shared__ float xL[4][64];
        xL[t >> 6][t & 63] = x[((b * NN_) + n0 + (t >> 6)) * NIN + (t & 63)];
        __syncthreads();

        const float4* w1r = (const float4*)(W1 + t * (2 * NIN));
        float psv[4] = {0.f, 0.f, 0.f, 0.f};
        float prv[4];
        float bv = b1[t];
        #pragma unroll
        for (int nn = 0; nn < 4; ++nn) prv[nn] = bv;

        #pragma unroll
        for (int f4 = 0; f4 < 16; ++f4) {          // sender half: cols 0..63
            float4 w = w1r[f4];
            #pragma unroll
            for (int nn = 0; nn < 4; ++nn)
                psv[nn] += w.x * xL[nn][4*f4+0] + w.y * xL[nn][4*f4+1]
                         + w.z * xL[nn][4*f4+2] + w.w * xL[nn][4*f4+3];
        }
        #pragma unroll
        for (int f4 = 0; f4 < 16; ++f4) {          // receiver half: cols 64..127
            float4 w = w1r[16 + f4];
            #pragma unroll
            for (int nn = 0; nn < 4; ++nn)
                prv[nn] += w.x * xL[nn][4*f4+0] + w.y * xL[nn][4*f4+1]
                         + w.z * xL[nn][4*f4+2] + w.w * xL[nn][4*f4+3];
        }
        #pragma unroll
        for (int nn = 0; nn < 4; ++nn) {
            pr[((b * NN_) + n0 + nn) * MH + t] = prv[nn];   // [b][n][k]
            ps[((b * NN_) + n0 + nn) * MH + t] = psv[nn];   // [b][n][k]
        }
    } else {
        int i = ((blk - 1024) << 8) + t;   // 0..16383, W2 is [MO][MH] row-major
        w2b[i] = f2bf(W2[i]);
    }
}

// ---------------------------------------------------------------------------
// Kernel 2: edge fc2 as bf16 MFMA + rtw-weighted segment sum.
// One block per (b, r): GEMM [128 sender-slots x 256] @ [256 x 64].
// 256 thr = 4 waves; wave w owns sender slots [32w, 32w+32) (2 M-tiles of 16)
// x all 4 N-tiles. A = relu(ps[sender]+pr[r]) built on the fly in bf16.
// mfma_f32_16x16x32_bf16 layouts (HW-measured, learn_hip m89/m120):
//   A[m=lane&15][k=(lane>>4)*8+j], B[k=(lane>>4)*8+j][n=lane&15],
//   C/D: col=lane&15, row=(lane>>4)*4+reg.
// Epilogue: relu(C+b2)*rtw, column-reduce in registers (shfl xor 16/32),
// cross-wave via tiny LDS. Slot 127 is padding (rtw=0).
// ---------------------------------------------------------------------------
__global__ __launch_bounds__(256) void edge_kernel(
    const float* __restrict__ rt, const float* __restrict__ b2,
    const float* __restrict__ ps, const float* __restrict__ pr,
    const short* __restrict__ w2b, float* __restrict__ agg)
{
    int blk = blockIdx.x;
    int b = blk >> 7;
    int r = blk & 127;
    int tid = threadIdx.x;
    int w = tid >> 6;
    int lane = tid & 63;
    int ml = lane & 15;
    int q  = lane >> 4;

    __shared__ float rtw_lds[128];
    __shared__ float red[4][64];
    if (tid < 128) {
        float v = 0.f;
        if (tid < 127) {
            const float* p = rt + ((size_t)(b * EDGES + r * 127 + tid)) * 2;
            v = p[0] + p[1];
        }
        rtw_lds[tid] = v;
    }
    __syncthreads();

    int slot0 = 32 * w + ml;          // M-tile 0 row
    int slot1 = slot0 + 16;           // M-tile 1 row
    int snd0 = slot0 + (slot0 >= r ? 1 : 0); if (snd0 > 127) snd0 = 127;
    int snd1 = slot1 + (slot1 >= r ? 1 : 0); if (snd1 > 127) snd1 = 127;

    const float* ps0 = ps + ((size_t)(b * NN_ + snd0)) * MH;
    const float* ps1 = ps + ((size_t)(b * NN_ + snd1)) * MH;
    const float* prb = pr + ((size_t)(b * NN_ + r)) * MH;
    const short8* w2v = (const short8*)w2b;   // [n][k/8]

    f32x4 acc[2][4];
    #pragma unroll
    for (int mt = 0; mt < 2; ++mt)
        #pragma unroll
        for (int nt = 0; nt < 4; ++nt)
            acc[mt][nt] = (f32x4){0.f, 0.f, 0.f, 0.f};

    #pragma unroll
    for (int kc = 0; kc < 8; ++kc) {
        int koff = 32 * kc + 8 * q;
        float4 p0 = *(const float4*)(prb + koff);
        float4 p1 = *(const float4*)(prb + koff + 4);
        float4 s00 = *(const float4*)(ps0 + koff);
        float4 s01 = *(const float4*)(ps0 + koff + 4);
        float4 s10 = *(const float4*)(ps1 + koff);
        float4 s11 = *(const float4*)(ps1 + koff + 4);

        short8 a0, a1;
        a0[0] = f2bf(fmaxf(s00.x + p0.x, 0.f));
        a0[1] = f2bf(fmaxf(s00.y + p0.y, 0.f));
        a0[2] = f2bf(fmaxf(s00.z + p0.z, 0.f));
        a0[3] = f2bf(fmaxf(s00.w + p0.w, 0.f));
        a0[4] = f2bf(fmaxf(s01.x + p1.x, 0.f));
        a0[5] = f2bf(fmaxf(s01.y + p1.y, 0.f));
        a0[6] = f2bf(fmaxf(s01.z + p1.z, 0.f));
        a0[7] = f2bf(fmaxf(s01.w + p1.w, 0.f));
        a1[0] = f2bf(fmaxf(s10.x + p0.x, 0.f));
        a1[1] = f2bf(fmaxf(s10.y + p0.y, 0.f));
        a1[2] = f2bf(fmaxf(s10.z + p0.z, 0.f));
        a1[3] = f2bf(fmaxf(s10.w + p0.w, 0.f));
        a1[4] = f2bf(fmaxf(s11.x + p1.x, 0.f));
        a1[5] = f2bf(fmaxf(s11.y + p1.y, 0.f));
        a1[6] = f2bf(fmaxf(s11.z + p1.z, 0.f));
        a1[7] = f2bf(fmaxf(s11.w + p1.w, 0.f));

        #pragma unroll
        for (int nt = 0; nt < 4; ++nt) {
            short8 bf = w2v[((16 * nt + ml) << 5) + (koff >> 3)];
            acc[0][nt] = __builtin_amdgcn_mfma_f32_16x16x32_bf16(a0, bf, acc[0][nt], 0, 0, 0);
            acc[1][nt] = __builtin_amdgcn_mfma_f32_16x16x32_bf16(a1, bf, acc[1][nt], 0, 0, 0);
        }
    }

    // epilogue: val = relu(C + b2[col]) * rtw[row-slot]; sum over 128 slots
    float b2c[4];
    #pragma unroll
    for (int nt = 0; nt < 4; ++nt) b2c[nt] = b2[16 * nt + ml];

    float colsum[4] = {0.f, 0.f, 0.f, 0.f};
    #pragma unroll
    for (int mt = 0; mt < 2; ++mt) {
        int slotbase = 32 * w + 16 * mt + 4 * q;
        #pragma unroll
        for (int reg = 0; reg < 4; ++reg) {
            float rw = rtw_lds[slotbase + reg];
            #pragma unroll
            for (int nt = 0; nt < 4; ++nt) {
                float v = fmaxf(acc[mt][nt][reg] + b2c[nt], 0.f) * rw;
                colsum[nt] += v;
            }
        }
    }
    #pragma unroll
    for (int nt = 0; nt < 4; ++nt) {
        colsum[nt] += __shfl_xor(colsum[nt], 16);
        colsum[nt] += __shfl_xor(colsum[nt], 32);
    }
    if (lane < 16) {
        #pragma unroll
        for (int nt = 0; nt < 4; ++nt) red[w][16 * nt + ml] = colsum[nt];
    }
    __syncthreads();
    if (tid < 64)
        agg[((size_t)(b * NN_ + r)) * MO + tid] =
            red[0][tid] + red[1][tid] + red[2][tid] + red[3][tid];
}

// ---------------------------------------------------------------------------
// Kernel 3: node MLP (64 -> 256 -> 256 -> 64). 4 nodes/block, grid 1024
// (was 8/block grid 512 = only 2 blocks/CU).
// ---------------------------------------------------------------------------
__global__ __launch_bounds__(256) void node_kernel(
    const float* __restrict__ agg, const float* __restrict__ O1,
    const float* __restrict__ b1o, const float* __restrict__ O2,
    const float* __restrict__ b2o, const float* __restrict__ O3,
    const float* __restrict__ b3o, float* __restrict__ out)
{
    int t  = threadIdx.x;
    int b  = blockIdx.x >> 5;
    int n0 = (blockIdx.x & 31) << 2;
    __shared__ float aggL[4][64];
    __shared__ float h1L[4][256];
    __shared__ float h2L[4][256];

    if (t < 256) aggL[t >> 6][t & 63] = agg[((b * NN_) + n0 + (t >> 6)) * MO + (t & 63)];
    __syncthreads();

    { // fc1: thread t = hidden unit p
        const float4* row = (const float4*)(O1 + t * MO);
        float s[4];
        float bv = b1o[t];
        #pragma unroll
        for (int nn = 0; nn < 4; ++nn) s[nn] = bv;
        #pragma unroll
        for (int f4 = 0; f4 < 16; ++f4) {
            float4 wv = row[f4];
            #pragma unroll
            for (int nn = 0; nn < 4; ++nn)
                s[nn] += wv.x*aggL[nn][4*f4+0] + wv.y*aggL[nn][4*f4+1]
                       + wv.z*aggL[nn][4*f4+2] + wv.w*aggL[nn][4*f4+3];
        }
        #pragma unroll
        for (int nn = 0; nn < 4; ++nn) h1L[nn][t] = fmaxf(s[nn], 0.f);
    }
    __syncthreads();

    { // fc2
        const float4* row = (const float4*)(O2 + t * NH);
        float s[4];
        float bv = b2o[t];
        #pragma unroll
        for (int nn = 0; nn < 4; ++nn) s[nn] = bv;
        for (int f4 = 0; f4 < 64; ++f4) {
            float4 wv = row[f4];
            #pragma unroll
            for (int nn = 0; nn < 4; ++nn)
                s[nn] += wv.x*h1L[nn][4*f4+0] + wv.y*h1L[nn][4*f4+1]
                       + wv.z*h1L[nn][4*f4+2] + wv.w*h1L[nn][4*f4+3];
        }
        #pragma unroll
        for (int nn = 0; nn < 4; ++nn) h2L[nn][t] = fmaxf(s[nn], 0.f);
    }
    __syncthreads();

    { // fc3: 256 (node, out) pairs
        int nn = t >> 6;     // 0..3
        int o  = t & 63;
        const float4* row = (const float4*)(O3 + o * NH);
        float s = b3o[o];
        for (int f4 = 0; f4 < 64; ++f4) {
            float4 wv = row[f4];
            s += wv.x*h2L[nn][4*f4+0] + wv.y*h2L[nn][4*f4+1]
               + wv.z*h2L[nn][4*f4+2] + wv.w*h2L[nn][4*f4+3];
        }
        out[((b * NN_) + n0 + nn) * NO + o] = s;
    }
}

// ---------------------------------------------------------------------------
extern "C" void kernel_launch(void* const* d_in, const int* in_sizes, int n_in,
                              void* d_out, int out_size, void* d_ws, size_t ws_size,
                              hipStream_t stream) {
    const float* x   = (const float*)d_in[0];
    const float* rt  = (const float*)d_in[3];
    const float* W1  = (const float*)d_in[4];
    const float* b1  = (const float*)d_in[5];
    const float* W2  = (const float*)d_in[6];
    const float* b2  = (const float*)d_in[7];
    const float* O1  = (const float*)d_in[8];
    const float* b1o = (const float*)d_in[9];
    const float* O2  = (const float*)d_in[10];
    const float* b2o = (const float*)d_in[11];
    const float* O3  = (const float*)d_in[12];
    const float* b3o = (const float*)d_in[13];

    float* ws  = (float*)d_ws;
    float* ps  = ws;
    float* pr  = ws + 1048576;
    short* w2b = (short*)(ws + 2097152);
    float* agg = ws + 2105344;
    float* out = (float*)d_out;

    hipLaunchKernelGGL(prep_kernel, dim3(1088), dim3(256), 0, stream,
                       x, W1, b1, W2, ps, pr, w2b);
    hipLaunchKernelGGL(edge_kernel, dim3(4096), dim3(256), 0, stream,
                       rt, b2, ps, pr, w2b, agg);
    hipLaunchKernelGGL(node_kernel, dim3(1024), dim3(256), 0, stream,
                       agg, O1, b1o, O2, b2o, O3, b3o, out);
}

// Round 3
// 210.537 us; speedup vs baseline: 2.5672x; 1.4166x over previous
//
#include <hip/hip_runtime.h>

#define BB 32
#define NN_ 128
#define NIN 64
#define MH 256
#define MO 64
#define NH 256
#define NO 64
#define EDGES 16256

typedef __attribute__((ext_vector_type(8))) short short8;   // 8 bf16 = 4 VGPRs
typedef __attribute__((ext_vector_type(4))) float f32x4;    // MFMA acc

// ws layout (floats):
//   psb: [B][32][128][8] bf16  off 0        = 1048576 shorts = 524288 floats
//   prb: [B][N][256]     bf16  off 524288   = 1048576 shorts = 524288 floats
//   w2b: [32][64][8]     bf16  off 1048576  = 16384 shorts  = 8192 floats
//   agg: [B][N][MO]      fp32  off 1056768  = 262144 floats
// total 1318912 floats = 5.28 MB

static __device__ __forceinline__ unsigned short f2bf(float f) {  // RNE
    unsigned u = __float_as_uint(f);
    u = (u + 0x7fffu + ((u >> 16) & 1u)) >> 16;
    return (unsigned short)u;
}

// pack two relu'd fp32 into packed bf16 (round-to-nearest, ties away)
static __device__ __forceinline__ unsigned bf_pack(float lo, float hi) {
    return __builtin_amdgcn_perm(__float_as_uint(hi) + 0x8000u,
                                 __float_as_uint(lo) + 0x8000u, 0x07060302u);
}

// ---------------------------------------------------------------------------
// Kernel 1: fc1 partials Ps/Pr in bf16 (Pr includes b1) + bf16 re-layout of W2.
//   psb[b][k>>3][node][k&7], prb[b][node][k], w2b[k>>3][n][k&7] (= W2[n][k])
// ---------------------------------------------------------------------------
__global__ __launch_bounds__(256) void prep_kernel(
    const float* __restrict__ x, const float* __restrict__ W1,
    const float* __restrict__ b1, const float* __restrict__ W2,
    unsigned short* __restrict__ psb, unsigned short* __restrict__ prb,
    unsigned short* __restrict__ w2b)
{
    int blk = blockIdx.x;
    int t = threadIdx.x;
    if (blk < 1024) {
        int b  = blk >> 5;
        int n0 = (blk & 31) << 2;
        __shared__ float xL[4][64];
        xL[t >> 6][t & 63] = x[((b * NN_) + n0 + (t >> 6)) * NIN + (t & 63)];
        __syncthreads();

        const float4* w1r = (const float4*)(W1 + t * (2 * NIN));
        float psv[4] = {0.f, 0.f, 0.f, 0.f};
        float prv[4];
        float bv = b1[t];
        #pragma unroll
        for (int nn = 0; nn < 4; ++nn) prv[nn] = bv;

        #pragma unroll
        for (int f4 = 0; f4 < 16; ++f4) {          // sender half: cols 0..63
            float4 w = w1r[f4];
            #pragma unroll
            for (int nn = 0; nn < 4; ++nn)
                psv[nn] += w.x * xL[nn][4*f4+0] + w.y * xL[nn][4*f4+1]
                         + w.z * xL[nn][4*f4+2] + w.w * xL[nn][4*f4+3];
        }
        #pragma unroll
        for (int f4 = 0; f4 < 16; ++f4) {          // receiver half: cols 64..127
            float4 w = w1r[16 + f4];
            #pragma unroll
            for (int nn = 0; nn < 4; ++nn)
                prv[nn] += w.x * xL[nn][4*f4+0] + w.y * xL[nn][4*f4+1]
                         + w.z * xL[nn][4*f4+2] + w.w * xL[nn][4*f4+3];
        }
        #pragma unroll
        for (int nn = 0; nn < 4; ++nn) {
            int n = n0 + nn;
            prb[((b * NN_) + n) * MH + t] = f2bf(prv[nn]);
            psb[(((b * 32) + (t >> 3)) * NN_ + n) * 8 + (t & 7)] = f2bf(psv[nn]);
        }
    } else {
        int i = ((blk - 1024) << 8) + t;   // 0..16383
        int kc4 = i >> 9, rem = i & 511;
        int n = rem >> 3, k7 = i & 7;
        int k = kc4 * 8 + k7;
        w2b[i] = f2bf(W2[n * MH + k]);     // w2b[kc4][n][k7] = W2[n][k]
    }
}

// ---------------------------------------------------------------------------
// Kernel 2: edge fc2 as bf16 MFMA + rtw-weighted segment sum.
// Block = (b, r); 4 waves x (2 M-tiles x 4 N-tiles). A built on the fly:
// relu(ps_bf[s]+pr_bf[r]) packed via v_perm. All quarter-wave loads are
// contiguous 256B segments thanks to the [k/8][node][8] layouts.
// ---------------------------------------------------------------------------
__global__ __launch_bounds__(256, 4) void edge_kernel(
    const float* __restrict__ rt, const float* __restrict__ b2,
    const unsigned short* __restrict__ psb, const unsigned short* __restrict__ prb,
    const unsigned short* __restrict__ w2b, float* __restrict__ agg)
{
    int blk = blockIdx.x;
    int b = blk >> 7;
    int r = blk & 127;
    int tid = threadIdx.x;
    int w = tid >> 6;
    int lane = tid & 63;
    int ml = lane & 15;
    int q  = lane >> 4;

    __shared__ float rtw_lds[128];
    __shared__ float red[4][64];
    if (tid < 128) {
        float v = 0.f;
        if (tid < 127) {
            const float* p = rt + ((size_t)(b * EDGES + r * 127 + tid)) * 2;
            v = p[0] + p[1];
        }
        rtw_lds[tid] = v;
    }
    __syncthreads();

    int slot0 = 32 * w + ml;
    int slot1 = slot0 + 16;
    int snd0 = slot0 + (slot0 >= r ? 1 : 0); if (snd0 > 127) snd0 = 127;
    int snd1 = slot1 + (slot1 >= r ? 1 : 0); if (snd1 > 127) snd1 = 127;

    const uint4* ps4 = (const uint4*)psb + (size_t)b * (32 * NN_);   // [kc4][node]
    const uint4* pr4 = (const uint4*)(prb + ((size_t)(b * NN_ + r)) * MH); // [kc4]
    const uint4* w24 = (const uint4*)w2b;                            // [kc4][n]

    f32x4 acc[2][4];
    #pragma unroll
    for (int mt = 0; mt < 2; ++mt)
        #pragma unroll
        for (int nt = 0; nt < 4; ++nt)
            acc[mt][nt] = (f32x4){0.f, 0.f, 0.f, 0.f};

    #pragma unroll
    for (int kc = 0; kc < 8; ++kc) {
        int kc4 = 4 * kc + q;
        uint4 upr = pr4[kc4];
        uint4 us0 = ps4[kc4 * NN_ + snd0];
        uint4 us1 = ps4[kc4 * NN_ + snd1];

        float plo[4], phi[4];
        plo[0] = __uint_as_float(upr.x << 16); phi[0] = __uint_as_float(upr.x & 0xffff0000u);
        plo[1] = __uint_as_float(upr.y << 16); phi[1] = __uint_as_float(upr.y & 0xffff0000u);
        plo[2] = __uint_as_float(upr.z << 16); phi[2] = __uint_as_float(upr.z & 0xffff0000u);
        plo[3] = __uint_as_float(upr.w << 16); phi[3] = __uint_as_float(upr.w & 0xffff0000u);

        uint4 a0u, a1u;
        {
            unsigned c;
            c = us0.x; a0u.x = bf_pack(fmaxf(__uint_as_float(c << 16) + plo[0], 0.f),
                                       fmaxf(__uint_as_float(c & 0xffff0000u) + phi[0], 0.f));
            c = us0.y; a0u.y = bf_pack(fmaxf(__uint_as_float(c << 16) + plo[1], 0.f),
                                       fmaxf(__uint_as_float(c & 0xffff0000u) + phi[1], 0.f));
            c = us0.z; a0u.z = bf_pack(fmaxf(__uint_as_float(c << 16) + plo[2], 0.f),
                                       fmaxf(__uint_as_float(c & 0xffff0000u) + phi[2], 0.f));
            c = us0.w; a0u.w = bf_pack(fmaxf(__uint_as_float(c << 16) + plo[3], 0.f),
                                       fmaxf(__uint_as_float(c & 0xffff0000u) + phi[3], 0.f));
            c = us1.x; a1u.x = bf_pack(fmaxf(__uint_as_float(c << 16) + plo[0], 0.f),
                                       fmaxf(__uint_as_float(c & 0xffff0000u) + phi[0], 0.f));
            c = us1.y; a1u.y = bf_pack(fmaxf(__uint_as_float(c << 16) + plo[1], 0.f),
                                       fmaxf(__uint_as_float(c & 0xffff0000u) + phi[1], 0.f));
            c = us1.z; a1u.z = bf_pack(fmaxf(__uint_as_float(c << 16) + plo[2], 0.f),
                                       fmaxf(__uint_as_float(c & 0xffff0000u) + phi[2], 0.f));
            c = us1.w; a1u.w = bf_pack(fmaxf(__uint_as_float(c << 16) + plo[3], 0.f),
                                       fmaxf(__uint_as_float(c & 0xffff0000u) + phi[3], 0.f));
        }
        short8 a0 = __builtin_bit_cast(short8, a0u);
        short8 a1 = __builtin_bit_cast(short8, a1u);

        #pragma unroll
        for (int nt = 0; nt < 4; ++nt) {
            uint4 uw = w24[kc4 * 64 + 16 * nt + ml];
            short8 bf = __builtin_bit_cast(short8, uw);
            acc[0][nt] = __builtin_amdgcn_mfma_f32_16x16x32_bf16(a0, bf, acc[0][nt], 0, 0, 0);
            acc[1][nt] = __builtin_amdgcn_mfma_f32_16x16x32_bf16(a1, bf, acc[1][nt], 0, 0, 0);
        }
    }

    // epilogue: val = relu(C + b2[col]) * rtw[slot]; sum over 128 slots
    float b2c[4];
    #pragma unroll
    for (int nt = 0; nt < 4; ++nt) b2c[nt] = b2[16 * nt + ml];

    float colsum[4] = {0.f, 0.f, 0.f, 0.f};
    #pragma unroll
    for (int mt = 0; mt < 2; ++mt) {
        int slotbase = 32 * w + 16 * mt + 4 * q;
        #pragma unroll
        for (int reg = 0; reg < 4; ++reg) {
            float rw = rtw_lds[slotbase + reg];
            #pragma unroll
            for (int nt = 0; nt < 4; ++nt)
                colsum[nt] += fmaxf(acc[mt][nt][reg] + b2c[nt], 0.f) * rw;
        }
    }
    #pragma unroll
    for (int nt = 0; nt < 4; ++nt) {
        colsum[nt] += __shfl_xor(colsum[nt], 16);
        colsum[nt] += __shfl_xor(colsum[nt], 32);
    }
    if (lane < 16) {
        #pragma unroll
        for (int nt = 0; nt < 4; ++nt) red[w][16 * nt + ml] = colsum[nt];
    }
    __syncthreads();
    if (tid < 64)
        agg[((size_t)(b * NN_ + r)) * MO + tid] =
            red[0][tid] + red[1][tid] + red[2][tid] + red[3][tid];
}

// ---------------------------------------------------------------------------
// Kernel 3: node MLP (64 -> 256 -> 256 -> 64), fp32. 8 nodes/block, grid 512.
// fc2 split 4-ways per row (k = f*16 + s*4: bank-staggered, conflict-free LDS
// broadcasts; O2 row reads coalesced 64B/4-lane) + shfl-xor reduce.
// ---------------------------------------------------------------------------
__global__ __launch_bounds__(256) void node_kernel(
    const float* __restrict__ agg, const float* __restrict__ O1,
    const float* __restrict__ b1o, const float* __restrict__ O2,
    const float* __restrict__ b2o, const float* __restrict__ O3,
    const float* __restrict__ b3o, float* __restrict__ out)
{
    int t  = threadIdx.x;
    int b  = blockIdx.x >> 4;
    int n0 = (blockIdx.x & 15) << 3;
    __shared__ float aggL[8][64];
    __shared__ float h1L[8][256];
    __shared__ float h2L[8][256];

    {
        int i = t, j = t + 256;
        aggL[i >> 6][i & 63] = agg[((b * NN_) + n0 + (i >> 6)) * MO + (i & 63)];
        aggL[j >> 6][j & 63] = agg[((b * NN_) + n0 + (j >> 6)) * MO + (j & 63)];
    }
    __syncthreads();

    { // fc1: thread t = hidden unit p (256)
        const float4* row = (const float4*)(O1 + t * MO);
        float s[8];
        float bv = b1o[t];
        #pragma unroll
        for (int nn = 0; nn < 8; ++nn) s[nn] = bv;
        #pragma unroll
        for (int f4 = 0; f4 < 16; ++f4) {
            float4 wv = row[f4];
            #pragma unroll
            for (int nn = 0; nn < 8; ++nn)
                s[nn] += wv.x*aggL[nn][4*f4+0] + wv.y*aggL[nn][4*f4+1]
                       + wv.z*aggL[nn][4*f4+2] + wv.w*aggL[nn][4*f4+3];
        }
        #pragma unroll
        for (int nn = 0; nn < 8; ++nn) h1L[nn][t] = fmaxf(s[nn], 0.f);
    }
    __syncthreads();

    { // fc2: row q = rr*64 + (t>>2), split s = t&3 over k = f*16 + s*4 + c
        int s4 = t & 3;
        #pragma unroll
        for (int rr = 0; rr < 4; ++rr) {
            int qq = rr * 64 + (t >> 2);
            const float* row = O2 + qq * NH;
            float part[8];
            #pragma unroll
            for (int nn = 0; nn < 8; ++nn) part[nn] = 0.f;
            #pragma unroll 4
            for (int f = 0; f < 16; ++f) {
                float4 wv = *(const float4*)(row + f * 16 + s4 * 4);
                #pragma unroll
                for (int nn = 0; nn < 8; ++nn) {
                    const float* hv = &h1L[nn][f * 16 + s4 * 4];
                    part[nn] += wv.x*hv[0] + wv.y*hv[1] + wv.z*hv[2] + wv.w*hv[3];
                }
            }
            #pragma unroll
            for (int nn = 0; nn < 8; ++nn) {
                float v = part[nn];
                v += __shfl_xor(v, 1);
                v += __shfl_xor(v, 2);
                if (s4 == 0) h2L[nn][qq] = fmaxf(v + b2o[qq], 0.f);
            }
        }
    }
    __syncthreads();

    { // fc3: 512 (node, out) pairs over 2 passes
        #pragma unroll
        for (int pass = 0; pass < 2; ++pass) {
            int id = pass * 256 + t;
            int nn = id >> 6;
            int o  = id & 63;
            const float4* row = (const float4*)(O3 + o * NH);
            float s = b3o[o];
            for (int f4 = 0; f4 < 64; ++f4) {
                float4 wv = row[f4];
                s += wv.x*h2L[nn][4*f4+0] + wv.y*h2L[nn][4*f4+1]
                   + wv.z*h2L[nn][4*f4+2] + wv.w*h2L[nn][4*f4+3];
            }
            out[((b * NN_) + n0 + nn) * NO + o] = s;
        }
    }
}

// ---------------------------------------------------------------------------
extern "C" void kernel_launch(void* const* d_in, const int* in_sizes, int n_in,
                              void* d_out, int out_size, void* d_ws, size_t ws_size,
                              hipStream_t stream) {
    const float* x   = (const float*)d_in[0];
    const float* rt  = (const float*)d_in[3];
    const float* W1  = (const float*)d_in[4];
    const float* b1  = (const float*)d_in[5];
    const float* W2  = (const float*)d_in[6];
    const float* b2  = (const float*)d_in[7];
    const float* O1  = (const float*)d_in[8];
    const float* b1o = (const float*)d_in[9];
    const float* O2  = (const float*)d_in[10];
    const float* b2o = (const float*)d_in[11];
    const float* O3  = (const float*)d_in[12];
    const float* b3o = (const float*)d_in[13];

    float* ws  = (float*)d_ws;
    unsigned short* psb = (unsigned short*)ws;
    unsigned short* prb = (unsigned short*)(ws + 524288);
    unsigned short* w2b = (unsigned short*)(ws + 1048576);
    float* agg = ws + 1056768;
    float* out = (float*)d_out;

    hipLaunchKernelGGL(prep_kernel, dim3(1088), dim3(256), 0, stream,
                       x, W1, b1, W2, psb, prb, w2b);
    hipLaunchKernelGGL(edge_kernel, dim3(4096), dim3(256), 0, stream,
                       rt, b2, psb, prb, w2b, agg);
    hipLaunchKernelGGL(node_kernel, dim3(512), dim3(256), 0, stream,
                       agg, O1, b1o, O2, b2o, O3, b3o, out);
}

// Round 4
// 152.581 us; speedup vs baseline: 3.5423x; 1.3798x over previous
//
#include <hip/hip_runtime.h>

#define BB 32
#define NN_ 128
#define NIN 64
#define MH 256
#define MO 64
#define NH 256
#define NO 64
#define EDGES 16256

typedef __attribute__((ext_vector_type(8))) short short8;   // 8 bf16 = 4 VGPRs
typedef __attribute__((ext_vector_type(4))) float f32x4;    // MFMA acc

// ws layout (floats):
//   psb: [B][32][128][8] bf16  off 0        = 524288 floats
//   prb: [B][N][256]     bf16  off 524288   = 524288 floats
//   w2b: [32][64][8]     bf16  off 1048576  = 8192 floats
//   agg: [B][N][MO]      fp32  off 1056768  = 262144 floats
//   o1b: [256][64]       bf16  off 1318912  = 8192 floats
//   o2b: [256][256]      bf16  off 1327104  = 32768 floats
//   o3b: [64][256]       bf16  off 1359872  = 8192 floats
// total 1368064 floats = 5.47 MB

static __device__ __forceinline__ unsigned short f2bf(float f) {  // RNE
    unsigned u = __float_as_uint(f);
    u = (u + 0x7fffu + ((u >> 16) & 1u)) >> 16;
    return (unsigned short)u;
}

// pack two fp32 into packed bf16 (round-half-away; sign-safe)
static __device__ __forceinline__ unsigned bf_pack(float lo, float hi) {
    return __builtin_amdgcn_perm(__float_as_uint(hi) + 0x8000u,
                                 __float_as_uint(lo) + 0x8000u, 0x07060302u);
}

// ---------------------------------------------------------------------------
// Kernel 1: fc1 partials Ps/Pr in bf16 (Pr includes b1), bf16 re-layout of W2,
// and bf16 casts of the node-MLP weights O1/O2/O3 (already [out][in] =
// B-fragment [n][k] layout — no transpose needed).
// ---------------------------------------------------------------------------
__global__ __launch_bounds__(256) void prep_kernel(
    const float* __restrict__ x, const float* __restrict__ W1,
    const float* __restrict__ b1, const float* __restrict__ W2,
    const float* __restrict__ O1, const float* __restrict__ O2,
    const float* __restrict__ O3,
    unsigned short* __restrict__ psb, unsigned short* __restrict__ prb,
    unsigned short* __restrict__ w2b, unsigned short* __restrict__ o1b,
    unsigned short* __restrict__ o2b, unsigned short* __restrict__ o3b)
{
    int blk = blockIdx.x;
    int t = threadIdx.x;
    if (blk < 1024) {
        int b  = blk >> 5;
        int n0 = (blk & 31) << 2;
        __shared__ float xL[4][64];
        xL[t >> 6][t & 63] = x[((b * NN_) + n0 + (t >> 6)) * NIN + (t & 63)];
        __syncthreads();

        const float4* w1r = (const float4*)(W1 + t * (2 * NIN));
        float psv[4] = {0.f, 0.f, 0.f, 0.f};
        float prv[4];
        float bv = b1[t];
        #pragma unroll
        for (int nn = 0; nn < 4; ++nn) prv[nn] = bv;

        #pragma unroll
        for (int f4 = 0; f4 < 16; ++f4) {          // sender half: cols 0..63
            float4 w = w1r[f4];
            #pragma unroll
            for (int nn = 0; nn < 4; ++nn)
                psv[nn] += w.x * xL[nn][4*f4+0] + w.y * xL[nn][4*f4+1]
                         + w.z * xL[nn][4*f4+2] + w.w * xL[nn][4*f4+3];
        }
        #pragma unroll
        for (int f4 = 0; f4 < 16; ++f4) {          // receiver half: cols 64..127
            float4 w = w1r[16 + f4];
            #pragma unroll
            for (int nn = 0; nn < 4; ++nn)
                prv[nn] += w.x * xL[nn][4*f4+0] + w.y * xL[nn][4*f4+1]
                         + w.z * xL[nn][4*f4+2] + w.w * xL[nn][4*f4+3];
        }
        #pragma unroll
        for (int nn = 0; nn < 4; ++nn) {
            int n = n0 + nn;
            prb[((b * NN_) + n) * MH + t] = f2bf(prv[nn]);
            psb[(((b * 32) + (t >> 3)) * NN_ + n) * 8 + (t & 7)] = f2bf(psv[nn]);
        }
    } else if (blk < 1088) {
        int i = ((blk - 1024) << 8) + t;   // 0..16383
        int kc4 = i >> 9, rem = i & 511;
        int n = rem >> 3, k7 = i & 7;
        int k = kc4 * 8 + k7;
        w2b[i] = f2bf(W2[n * MH + k]);     // w2b[kc4][n][k7] = W2[n][k]
    } else {
        int i = ((blk - 1088) << 8) + t;   // 0..98303
        if (i < 16384)       o1b[i]         = f2bf(O1[i]);
        else if (i < 81920)  o2b[i - 16384] = f2bf(O2[i - 16384]);
        else                 o3b[i - 81920] = f2bf(O3[i - 81920]);
    }
}

// ---------------------------------------------------------------------------
// Kernel 2: edge fc2 as bf16 MFMA + rtw-weighted segment sum. (unchanged)
// ---------------------------------------------------------------------------
__global__ __launch_bounds__(256, 4) void edge_kernel(
    const float* __restrict__ rt, const float* __restrict__ b2,
    const unsigned short* __restrict__ psb, const unsigned short* __restrict__ prb,
    const unsigned short* __restrict__ w2b, float* __restrict__ agg)
{
    int blk = blockIdx.x;
    int b = blk >> 7;
    int r = blk & 127;
    int tid = threadIdx.x;
    int w = tid >> 6;
    int lane = tid & 63;
    int ml = lane & 15;
    int q  = lane >> 4;

    __shared__ float rtw_lds[128];
    __shared__ float red[4][64];
    if (tid < 128) {
        float v = 0.f;
        if (tid < 127) {
            const float* p = rt + ((size_t)(b * EDGES + r * 127 + tid)) * 2;
            v = p[0] + p[1];
        }
        rtw_lds[tid] = v;
    }
    __syncthreads();

    int slot0 = 32 * w + ml;
    int slot1 = slot0 + 16;
    int snd0 = slot0 + (slot0 >= r ? 1 : 0); if (snd0 > 127) snd0 = 127;
    int snd1 = slot1 + (slot1 >= r ? 1 : 0); if (snd1 > 127) snd1 = 127;

    const uint4* ps4 = (const uint4*)psb + (size_t)b * (32 * NN_);   // [kc4][node]
    const uint4* pr4 = (const uint4*)(prb + ((size_t)(b * NN_ + r)) * MH); // [kc4]
    const uint4* w24 = (const uint4*)w2b;                            // [kc4][n]

    f32x4 acc[2][4];
    #pragma unroll
    for (int mt = 0; mt < 2; ++mt)
        #pragma unroll
        for (int nt = 0; nt < 4; ++nt)
            acc[mt][nt] = (f32x4){0.f, 0.f, 0.f, 0.f};

    #pragma unroll
    for (int kc = 0; kc < 8; ++kc) {
        int kc4 = 4 * kc + q;
        uint4 upr = pr4[kc4];
        uint4 us0 = ps4[kc4 * NN_ + snd0];
        uint4 us1 = ps4[kc4 * NN_ + snd1];

        float plo[4], phi[4];
        plo[0] = __uint_as_float(upr.x << 16); phi[0] = __uint_as_float(upr.x & 0xffff0000u);
        plo[1] = __uint_as_float(upr.y << 16); phi[1] = __uint_as_float(upr.y & 0xffff0000u);
        plo[2] = __uint_as_float(upr.z << 16); phi[2] = __uint_as_float(upr.z & 0xffff0000u);
        plo[3] = __uint_as_float(upr.w << 16); phi[3] = __uint_as_float(upr.w & 0xffff0000u);

        uint4 a0u, a1u;
        {
            unsigned c;
            c = us0.x; a0u.x = bf_pack(fmaxf(__uint_as_float(c << 16) + plo[0], 0.f),
                                       fmaxf(__uint_as_float(c & 0xffff0000u) + phi[0], 0.f));
            c = us0.y; a0u.y = bf_pack(fmaxf(__uint_as_float(c << 16) + plo[1], 0.f),
                                       fmaxf(__uint_as_float(c & 0xffff0000u) + phi[1], 0.f));
            c = us0.z; a0u.z = bf_pack(fmaxf(__uint_as_float(c << 16) + plo[2], 0.f),
                                       fmaxf(__uint_as_float(c & 0xffff0000u) + phi[2], 0.f));
            c = us0.w; a0u.w = bf_pack(fmaxf(__uint_as_float(c << 16) + plo[3], 0.f),
                                       fmaxf(__uint_as_float(c & 0xffff0000u) + phi[3], 0.f));
            c = us1.x; a1u.x = bf_pack(fmaxf(__uint_as_float(c << 16) + plo[0], 0.f),
                                       fmaxf(__uint_as_float(c & 0xffff0000u) + phi[0], 0.f));
            c = us1.y; a1u.y = bf_pack(fmaxf(__uint_as_float(c << 16) + plo[1], 0.f),
                                       fmaxf(__uint_as_float(c & 0xffff0000u) + phi[1], 0.f));
            c = us1.z; a1u.z = bf_pack(fmaxf(__uint_as_float(c << 16) + plo[2], 0.f),
                                       fmaxf(__uint_as_float(c & 0xffff0000u) + phi[2], 0.f));
            c = us1.w; a1u.w = bf_pack(fmaxf(__uint_as_float(c << 16) + plo[3], 0.f),
                                       fmaxf(__uint_as_float(c & 0xffff0000u) + phi[3], 0.f));
        }
        short8 a0 = __builtin_bit_cast(short8, a0u);
        short8 a1 = __builtin_bit_cast(short8, a1u);

        #pragma unroll
        for (int nt = 0; nt < 4; ++nt) {
            uint4 uw = w24[kc4 * 64 + 16 * nt + ml];
            short8 bf = __builtin_bit_cast(short8, uw);
            acc[0][nt] = __builtin_amdgcn_mfma_f32_16x16x32_bf16(a0, bf, acc[0][nt], 0, 0, 0);
            acc[1][nt] = __builtin_amdgcn_mfma_f32_16x16x32_bf16(a1, bf, acc[1][nt], 0, 0, 0);
        }
    }

    float b2c[4];
    #pragma unroll
    for (int nt = 0; nt < 4; ++nt) b2c[nt] = b2[16 * nt + ml];

    float colsum[4] = {0.f, 0.f, 0.f, 0.f};
    #pragma unroll
    for (int mt = 0; mt < 2; ++mt) {
        int slotbase = 32 * w + 16 * mt + 4 * q;
        #pragma unroll
        for (int reg = 0; reg < 4; ++reg) {
            float rw = rtw_lds[slotbase + reg];
            #pragma unroll
            for (int nt = 0; nt < 4; ++nt)
                colsum[nt] += fmaxf(acc[mt][nt][reg] + b2c[nt], 0.f) * rw;
        }
    }
    #pragma unroll
    for (int nt = 0; nt < 4; ++nt) {
        colsum[nt] += __shfl_xor(colsum[nt], 16);
        colsum[nt] += __shfl_xor(colsum[nt], 32);
    }
    if (lane < 16) {
        #pragma unroll
        for (int nt = 0; nt < 4; ++nt) red[w][16 * nt + ml] = colsum[nt];
    }
    __syncthreads();
    if (tid < 64)
        agg[((size_t)(b * NN_ + r)) * MO + tid] =
            red[0][tid] + red[1][tid] + red[2][tid] + red[3][tid];
}

// ---------------------------------------------------------------------------
// Kernel 3: node MLP as 3 chained bf16 MFMAs. Block = 16 rows x 256 thr
// (4 waves; wave w owns N-tiles w*4..w*4+3), grid 256. Activations round-trip
// through LDS in A-fragment layout [m][k], row pad +8 shorts (2-way bank
// aliasing = free). Weights are [out][in] row-major bf16 = B-fragment layout.
// ---------------------------------------------------------------------------
__global__ __launch_bounds__(256) void node_kernel(
    const float* __restrict__ agg,
    const unsigned short* __restrict__ O1b, const float* __restrict__ b1o,
    const unsigned short* __restrict__ O2b, const float* __restrict__ b2o,
    const unsigned short* __restrict__ O3b, const float* __restrict__ b3o,
    float* __restrict__ out)
{
    int tid = threadIdx.x;
    int w = tid >> 6, lane = tid & 63, ml = lane & 15, q = lane >> 4;
    int row0 = blockIdx.x << 4;

    __shared__ unsigned short h1L[16][264];
    __shared__ unsigned short h2L[16][264];

    // fc1 A-fragments from agg (fp32 -> bf16; agg >= 0 so pack is sign-safe)
    short8 aA[2];
    #pragma unroll
    for (int s = 0; s < 2; ++s) {
        const float* base = agg + (size_t)(row0 + ml) * MO + 32 * s + q * 8;
        float4 f0 = *(const float4*)base;
        float4 f1 = *(const float4*)(base + 4);
        uint4 u;
        u.x = bf_pack(f0.x, f0.y);
        u.y = bf_pack(f0.z, f0.w);
        u.z = bf_pack(f1.x, f1.y);
        u.w = bf_pack(f1.z, f1.w);
        aA[s] = __builtin_bit_cast(short8, u);
    }

    // fc1: [16 x 64] @ [64 x 256]
    #pragma unroll
    for (int nt = 0; nt < 4; ++nt) {
        int ntg = w * 4 + nt;
        f32x4 acc = (f32x4){0.f, 0.f, 0.f, 0.f};
        #pragma unroll
        for (int s = 0; s < 2; ++s) {
            uint4 uw = *(const uint4*)(O1b + (size_t)(ntg * 16 + ml) * 64 + 32 * s + q * 8);
            acc = __builtin_amdgcn_mfma_f32_16x16x32_bf16(
                aA[s], __builtin_bit_cast(short8, uw), acc, 0, 0, 0);
        }
        float bv = b1o[ntg * 16 + ml];
        #pragma unroll
        for (int reg = 0; reg < 4; ++reg)
            h1L[q * 4 + reg][ntg * 16 + ml] = f2bf(fmaxf(acc[reg] + bv, 0.f));
    }
    __syncthreads();

    // fc2: [16 x 256] @ [256 x 256]
    short8 aH[8];
    #pragma unroll
    for (int ks = 0; ks < 8; ++ks)
        aH[ks] = *(const short8*)&h1L[ml][32 * ks + q * 8];
    #pragma unroll
    for (int nt = 0; nt < 4; ++nt) {
        int ntg = w * 4 + nt;
        const unsigned short* wrow = O2b + (size_t)(ntg * 16 + ml) * NH + q * 8;
        f32x4 acc = (f32x4){0.f, 0.f, 0.f, 0.f};
        #pragma unroll
        for (int ks = 0; ks < 8; ++ks) {
            uint4 uw = *(const uint4*)(wrow + 32 * ks);
            acc = __builtin_amdgcn_mfma_f32_16x16x32_bf16(
                aH[ks], __builtin_bit_cast(short8, uw), acc, 0, 0, 0);
        }
        float bv = b2o[ntg * 16 + ml];
        #pragma unroll
        for (int reg = 0; reg < 4; ++reg)
            h2L[q * 4 + reg][ntg * 16 + ml] = f2bf(fmaxf(acc[reg] + bv, 0.f));
    }
    __syncthreads();

    // fc3: [16 x 256] @ [256 x 64], wave w owns N-tile w
    #pragma unroll
    for (int ks = 0; ks < 8; ++ks)
        aH[ks] = *(const short8*)&h2L[ml][32 * ks + q * 8];
    {
        const unsigned short* wrow = O3b + (size_t)(w * 16 + ml) * NH + q * 8;
        f32x4 acc = (f32x4){0.f, 0.f, 0.f, 0.f};
        #pragma unroll
        for (int ks = 0; ks < 8; ++ks) {
            uint4 uw = *(const uint4*)(wrow + 32 * ks);
            acc = __builtin_amdgcn_mfma_f32_16x16x32_bf16(
                aH[ks], __builtin_bit_cast(short8, uw), acc, 0, 0, 0);
        }
        float bv = b3o[w * 16 + ml];
        #pragma unroll
        for (int reg = 0; reg < 4; ++reg)
            out[(size_t)(row0 + q * 4 + reg) * NO + w * 16 + ml] = acc[reg] + bv;
    }
}

// ---------------------------------------------------------------------------
extern "C" void kernel_launch(void* const* d_in, const int* in_sizes, int n_in,
                              void* d_out, int out_size, void* d_ws, size_t ws_size,
                              hipStream_t stream) {
    const float* x   = (const float*)d_in[0];
    const float* rt  = (const float*)d_in[3];
    const float* W1  = (const float*)d_in[4];
    const float* b1  = (const float*)d_in[5];
    const float* W2  = (const float*)d_in[6];
    const float* b2  = (const float*)d_in[7];
    const float* O1  = (const float*)d_in[8];
    const float* b1o = (const float*)d_in[9];
    const float* O2  = (const float*)d_in[10];
    const float* b2o = (const float*)d_in[11];
    const float* O3  = (const float*)d_in[12];
    const float* b3o = (const float*)d_in[13];

    float* ws  = (float*)d_ws;
    unsigned short* psb = (unsigned short*)ws;
    unsigned short* prb = (unsigned short*)(ws + 524288);
    unsigned short* w2b = (unsigned short*)(ws + 1048576);
    float* agg = ws + 1056768;
    unsigned short* o1b = (unsigned short*)(ws + 1318912);
    unsigned short* o2b = (unsigned short*)(ws + 1327104);
    unsigned short* o3b = (unsigned short*)(ws + 1359872);
    float* out = (float*)d_out;

    hipLaunchKernelGGL(prep_kernel, dim3(1472), dim3(256), 0, stream,
                       x, W1, b1, W2, O1, O2, O3, psb, prb, w2b, o1b, o2b, o3b);
    hipLaunchKernelGGL(edge_kernel, dim3(4096), dim3(256), 0, stream,
                       rt, b2, psb, prb, w2b, agg);
    hipLaunchKernelGGL(node_kernel, dim3(256), dim3(256), 0, stream,
                       agg, o1b, b1o, o2b, b2o, o3b, b3o, out);
}

// Round 5
// 130.327 us; speedup vs baseline: 4.1471x; 1.1708x over previous
//
#include <hip/hip_runtime.h>

#define BB 32
#define NN_ 128
#define NIN 64
#define MH 256
#define MO 64
#define NH 256
#define NO 64
#define EDGES 16256

typedef __attribute__((ext_vector_type(8))) short short8;   // 8 bf16 = 4 VGPRs
typedef __attribute__((ext_vector_type(4))) float f32x4;    // MFMA acc

// ws layout (floats):
//   psb: [B][32][128][8] bf16  off 0        = 524288 floats
//   prb: [B][N][256]     bf16  off 524288   = 524288 floats
//   w2b: [32][64][8]     bf16  off 1048576  = 8192 floats
//   agg: [B][N][MO]      fp32  off 1056768  = 262144 floats
//   o1b: [256][64]       bf16  off 1318912  = 8192 floats
//   o2b: [256][256]      bf16  off 1327104  = 32768 floats
//   o3b: [64][256]       bf16  off 1359872  = 8192 floats

static __device__ __forceinline__ unsigned short f2bf(float f) {  // RNE-ish
    unsigned u = __float_as_uint(f);
    u = (u + 0x7fffu + ((u >> 16) & 1u)) >> 16;
    return (unsigned short)u;
}

// pack two fp32 into packed bf16 (round-half-away; valid for any sign)
static __device__ __forceinline__ unsigned bf_pack(float lo, float hi) {
    return __builtin_amdgcn_perm(__float_as_uint(hi) + 0x8000u,
                                 __float_as_uint(lo) + 0x8000u, 0x07060302u);
}

static __device__ __forceinline__ short8 pack8(float4 f0, float4 f1) {
    uint4 u;
    u.x = bf_pack(f0.x, f0.y);
    u.y = bf_pack(f0.z, f0.w);
    u.z = bf_pack(f1.x, f1.y);
    u.w = bf_pack(f1.z, f1.w);
    return __builtin_bit_cast(short8, u);
}

static __device__ __forceinline__ void unpack8(uint4 u, float* f) {
    f[0] = __uint_as_float(u.x << 16); f[1] = __uint_as_float(u.x & 0xffff0000u);
    f[2] = __uint_as_float(u.y << 16); f[3] = __uint_as_float(u.y & 0xffff0000u);
    f[4] = __uint_as_float(u.z << 16); f[5] = __uint_as_float(u.z & 0xffff0000u);
    f[6] = __uint_as_float(u.w << 16); f[7] = __uint_as_float(u.w & 0xffff0000u);
}

static __device__ __forceinline__ short8 buildA(const float* s, const float* p) {
    uint4 u;
    u.x = bf_pack(fmaxf(s[0] + p[0], 0.f), fmaxf(s[1] + p[1], 0.f));
    u.y = bf_pack(fmaxf(s[2] + p[2], 0.f), fmaxf(s[3] + p[3], 0.f));
    u.z = bf_pack(fmaxf(s[4] + p[4], 0.f), fmaxf(s[5] + p[5], 0.f));
    u.w = bf_pack(fmaxf(s[6] + p[6], 0.f), fmaxf(s[7] + p[7], 0.f));
    return __builtin_bit_cast(short8, u);
}

// ---------------------------------------------------------------------------
// Kernel 1: prep.
//   blocks 0..255   : fc1 partials via bf16 MFMA. Block = 16 rows of x
//                     ([4096 x 64] @ W1^T halves -> ps, pr(+b1)), outputs
//                     stored bf16 into psb [b][k/8][node][8] / prb [b][node][k].
//   blocks 256..319 : W2 -> bf16 re-layout w2b[k/8][n][8]
//   blocks 320..703 : O1/O2/O3 -> bf16 casts (already B-fragment layout)
// ---------------------------------------------------------------------------
__global__ __launch_bounds__(256) void prep_kernel(
    const float* __restrict__ x, const float* __restrict__ W1,
    const float* __restrict__ b1, const float* __restrict__ W2,
    const float* __restrict__ O1, const float* __restrict__ O2,
    const float* __restrict__ O3,
    unsigned short* __restrict__ psb, unsigned short* __restrict__ prb,
    unsigned short* __restrict__ w2b, unsigned short* __restrict__ o1b,
    unsigned short* __restrict__ o2b, unsigned short* __restrict__ o3b)
{
    int blk = blockIdx.x;
    int t = threadIdx.x;
    if (blk < 256) {
        int row0 = blk << 4;          // 16 consecutive global rows (b = blk>>3)
        int b = blk >> 3;
        int w = t >> 6, lane = t & 63, ml = lane & 15, q = lane >> 4;

        // A fragments: x rows row0..row0+15, K=64 over two MFMA k-steps
        short8 aX[2];
        #pragma unroll
        for (int s = 0; s < 2; ++s) {
            const float* base = x + (size_t)(row0 + ml) * NIN + s * 32 + q * 8;
            aX[s] = pack8(*(const float4*)base, *(const float4*)(base + 4));
        }

        #pragma unroll
        for (int half = 0; half < 2; ++half) {     // 0 = sender(ps), 1 = recv(pr)
            #pragma unroll
            for (int nt = 0; nt < 4; ++nt) {
                int col = w * 64 + nt * 16 + ml;   // output unit h (0..255)
                const float* wrow = W1 + (size_t)col * (2 * NIN) + half * 64 + q * 8;
                f32x4 acc = (f32x4){0.f, 0.f, 0.f, 0.f};
                #pragma unroll
                for (int s = 0; s < 2; ++s) {
                    short8 bw = pack8(*(const float4*)(wrow + 32 * s),
                                      *(const float4*)(wrow + 32 * s + 4));
                    acc = __builtin_amdgcn_mfma_f32_16x16x32_bf16(aX[s], bw, acc, 0, 0, 0);
                }
                if (half == 0) {
                    #pragma unroll
                    for (int reg = 0; reg < 4; ++reg) {
                        int n = (row0 + q * 4 + reg) & 127;
                        psb[((size_t)(b * 32 + (col >> 3)) * NN_ + n) * 8 + (col & 7)]
                            = f2bf(acc[reg]);
                    }
                } else {
                    float bv = b1[col];
                    #pragma unroll
                    for (int reg = 0; reg < 4; ++reg) {
                        int n = (row0 + q * 4 + reg) & 127;
                        prb[((size_t)(b * NN_) + n) * MH + col] = f2bf(acc[reg] + bv);
                    }
                }
            }
        }
    } else if (blk < 320) {
        int i = ((blk - 256) << 8) + t;   // 0..16383
        int kc4 = i >> 9, rem = i & 511;
        int n = rem >> 3, k7 = i & 7;
        w2b[i] = f2bf(W2[n * MH + kc4 * 8 + k7]);   // w2b[kc4][n][k7] = W2[n][k]
    } else {
        int i = ((blk - 320) << 8) + t;   // 0..98303
        if (i < 16384)       o1b[i]         = f2bf(O1[i]);
        else if (i < 81920)  o2b[i - 16384] = f2bf(O2[i - 16384]);
        else                 o3b[i - 81920] = f2bf(O3[i - 81920]);
    }
}

// ---------------------------------------------------------------------------
// Kernel 2: edge fc2 as bf16 MFMA + rtw-weighted segment sum.
// Block = (b, receiver pair r0,r1). DENSE sender mapping: slot = sender,
// self-edge masked via rtw=0 -> ps fragments shared across both receivers,
// w2 fragments amortized 2x. 4 waves; wave w owns slots [32w,32w+32)
// (2 M-tiles) x 4 N-tiles x 2 receivers = 16 MFMA per k-step.
// ---------------------------------------------------------------------------
__global__ __launch_bounds__(256, 3) void edge_kernel(
    const float* __restrict__ rt, const float* __restrict__ b2,
    const unsigned short* __restrict__ psb, const unsigned short* __restrict__ prb,
    const unsigned short* __restrict__ w2b, float* __restrict__ agg)
{
    int blk = blockIdx.x;
    int b = blk >> 6;
    int r0 = (blk & 63) << 1;
    int tid = threadIdx.x;
    int w = tid >> 6, lane = tid & 63, ml = lane & 15, q = lane >> 4;

    __shared__ float rtw_lds[2][128];
    __shared__ float red[2][4][64];
    {
        int rr = tid >> 7, s = tid & 127;
        int r = r0 + rr;
        float v = 0.f;
        if (s != r) {
            int e = r * 127 + s - (s > r ? 1 : 0);
            const float* p = rt + ((size_t)(b * EDGES + e)) * 2;
            v = p[0] + p[1];
        }
        rtw_lds[rr][s] = v;
    }
    __syncthreads();

    int slot0 = 32 * w + ml;
    int slot1 = slot0 + 16;

    const uint4* ps4 = (const uint4*)psb + (size_t)b * (32 * NN_);       // [kc4][node]
    const uint4* pr4_0 = (const uint4*)(prb + ((size_t)(b * NN_ + r0)) * MH);
    const uint4* pr4_1 = (const uint4*)(prb + ((size_t)(b * NN_ + r0 + 1)) * MH);
    const uint4* w24 = (const uint4*)w2b;                                // [kc4][n]

    f32x4 acc[2][2][4];   // [receiver][m-tile][n-tile]
    #pragma unroll
    for (int rr = 0; rr < 2; ++rr)
        #pragma unroll
        for (int mt = 0; mt < 2; ++mt)
            #pragma unroll
            for (int nt = 0; nt < 4; ++nt)
                acc[rr][mt][nt] = (f32x4){0.f, 0.f, 0.f, 0.f};

    #pragma unroll
    for (int kc = 0; kc < 8; ++kc) {
        int kc4 = 4 * kc + q;
        uint4 us0 = ps4[kc4 * NN_ + slot0];
        uint4 us1 = ps4[kc4 * NN_ + slot1];
        uint4 up0 = pr4_0[kc4];
        uint4 up1 = pr4_1[kc4];

        float s0f[8], s1f[8], p0f[8], p1f[8];
        unpack8(us0, s0f); unpack8(us1, s1f);
        unpack8(up0, p0f); unpack8(up1, p1f);

        short8 a00 = buildA(s0f, p0f);   // r0, m-tile 0
        short8 a01 = buildA(s1f, p0f);   // r0, m-tile 1
        short8 a10 = buildA(s0f, p1f);   // r1, m-tile 0
        short8 a11 = buildA(s1f, p1f);   // r1, m-tile 1

        #pragma unroll
        for (int nt = 0; nt < 4; ++nt) {
            short8 bw = __builtin_bit_cast(short8, w24[kc4 * 64 + 16 * nt + ml]);
            acc[0][0][nt] = __builtin_amdgcn_mfma_f32_16x16x32_bf16(a00, bw, acc[0][0][nt], 0, 0, 0);
            acc[0][1][nt] = __builtin_amdgcn_mfma_f32_16x16x32_bf16(a01, bw, acc[0][1][nt], 0, 0, 0);
            acc[1][0][nt] = __builtin_amdgcn_mfma_f32_16x16x32_bf16(a10, bw, acc[1][0][nt], 0, 0, 0);
            acc[1][1][nt] = __builtin_amdgcn_mfma_f32_16x16x32_bf16(a11, bw, acc[1][1][nt], 0, 0, 0);
        }
    }

    float b2c[4];
    #pragma unroll
    for (int nt = 0; nt < 4; ++nt) b2c[nt] = b2[16 * nt + ml];

    #pragma unroll
    for (int rr = 0; rr < 2; ++rr) {
        float colsum[4] = {0.f, 0.f, 0.f, 0.f};
        #pragma unroll
        for (int mt = 0; mt < 2; ++mt) {
            int slotbase = 32 * w + 16 * mt + 4 * q;
            #pragma unroll
            for (int reg = 0; reg < 4; ++reg) {
                float rw = rtw_lds[rr][slotbase + reg];
                #pragma unroll
                for (int nt = 0; nt < 4; ++nt)
                    colsum[nt] += fmaxf(acc[rr][mt][nt][reg] + b2c[nt], 0.f) * rw;
            }
        }
        #pragma unroll
        for (int nt = 0; nt < 4; ++nt) {
            colsum[nt] += __shfl_xor(colsum[nt], 16);
            colsum[nt] += __shfl_xor(colsum[nt], 32);
        }
        if (lane < 16) {
            #pragma unroll
            for (int nt = 0; nt < 4; ++nt) red[rr][w][16 * nt + ml] = colsum[nt];
        }
    }
    __syncthreads();
    if (tid < 128) {
        int rr = tid >> 6, o = tid & 63;
        agg[((size_t)(b * NN_ + r0 + rr)) * MO + o] =
            red[rr][0][o] + red[rr][1][o] + red[rr][2][o] + red[rr][3][o];
    }
}

// ---------------------------------------------------------------------------
// Kernel 3: node MLP as 3 chained bf16 MFMAs (unchanged from R4).
// ---------------------------------------------------------------------------
__global__ __launch_bounds__(256) void node_kernel(
    const float* __restrict__ agg,
    const unsigned short* __restrict__ O1b, const float* __restrict__ b1o,
    const unsigned short* __restrict__ O2b, const float* __restrict__ b2o,
    const unsigned short* __restrict__ O3b, const float* __restrict__ b3o,
    float* __restrict__ out)
{
    int tid = threadIdx.x;
    int w = tid >> 6, lane = tid & 63, ml = lane & 15, q = lane >> 4;
    int row0 = blockIdx.x << 4;

    __shared__ unsigned short h1L[16][264];
    __shared__ unsigned short h2L[16][264];

    short8 aA[2];
    #pragma unroll
    for (int s = 0; s < 2; ++s) {
        const float* base = agg + (size_t)(row0 + ml) * MO + 32 * s + q * 8;
        aA[s] = pack8(*(const float4*)base, *(const float4*)(base + 4));
    }

    // fc1: [16 x 64] @ [64 x 256]
    #pragma unroll
    for (int nt = 0; nt < 4; ++nt) {
        int ntg = w * 4 + nt;
        f32x4 acc = (f32x4){0.f, 0.f, 0.f, 0.f};
        #pragma unroll
        for (int s = 0; s < 2; ++s) {
            uint4 uw = *(const uint4*)(O1b + (size_t)(ntg * 16 + ml) * 64 + 32 * s + q * 8);
            acc = __builtin_amdgcn_mfma_f32_16x16x32_bf16(
                aA[s], __builtin_bit_cast(short8, uw), acc, 0, 0, 0);
        }
        float bv = b1o[ntg * 16 + ml];
        #pragma unroll
        for (int reg = 0; reg < 4; ++reg)
            h1L[q * 4 + reg][ntg * 16 + ml] = f2bf(fmaxf(acc[reg] + bv, 0.f));
    }
    __syncthreads();

    // fc2: [16 x 256] @ [256 x 256]
    short8 aH[8];
    #pragma unroll
    for (int ks = 0; ks < 8; ++ks)
        aH[ks] = *(const short8*)&h1L[ml][32 * ks + q * 8];
    #pragma unroll
    for (int nt = 0; nt < 4; ++nt) {
        int ntg = w * 4 + nt;
        const unsigned short* wrow = O2b + (size_t)(ntg * 16 + ml) * NH + q * 8;
        f32x4 acc = (f32x4){0.f, 0.f, 0.f, 0.f};
        #pragma unroll
        for (int ks = 0; ks < 8; ++ks) {
            uint4 uw = *(const uint4*)(wrow + 32 * ks);
            acc = __builtin_amdgcn_mfma_f32_16x16x32_bf16(
                aH[ks], __builtin_bit_cast(short8, uw), acc, 0, 0, 0);
        }
        float bv = b2o[ntg * 16 + ml];
        #pragma unroll
        for (int reg = 0; reg < 4; ++reg)
            h2L[q * 4 + reg][ntg * 16 + ml] = f2bf(fmaxf(acc[reg] + bv, 0.f));
    }
    __syncthreads();

    // fc3: [16 x 256] @ [256 x 64]
    #pragma unroll
    for (int ks = 0; ks < 8; ++ks)
        aH[ks] = *(const short8*)&h2L[ml][32 * ks + q * 8];
    {
        const unsigned short* wrow = O3b + (size_t)(w * 16 + ml) * NH + q * 8;
        f32x4 acc = (f32x4){0.f, 0.f, 0.f, 0.f};
        #pragma unroll
        for (int ks = 0; ks < 8; ++ks) {
            uint4 uw = *(const uint4*)(wrow + 32 * ks);
            acc = __builtin_amdgcn_mfma_f32_16x16x32_bf16(
                aH[ks], __builtin_bit_cast(short8, uw), acc, 0, 0, 0);
        }
        float bv = b3o[w * 16 + ml];
        #pragma unroll
        for (int reg = 0; reg < 4; ++reg)
            out[(size_t)(row0 + q * 4 + reg) * NO + w * 16 + ml] = acc[reg] + bv;
    }
}

// ---------------------------------------------------------------------------
extern "C" void kernel_launch(void* const* d_in, const int* in_sizes, int n_in,
                              void* d_out, int out_size, void* d_ws, size_t ws_size,
                              hipStream_t stream) {
    const float* x   = (const float*)d_in[0];
    const float* rt  = (const float*)d_in[3];
    const float* W1  = (const float*)d_in[4];
    const float* b1  = (const float*)d_in[5];
    const float* W2  = (const float*)d_in[6];
    const float* b2  = (const float*)d_in[7];
    const float* O1  = (const float*)d_in[8];
    const float* b1o = (const float*)d_in[9];
    const float* O2  = (const float*)d_in[10];
    const float* b2o = (const float*)d_in[11];
    const float* O3  = (const float*)d_in[12];
    const float* b3o = (const float*)d_in[13];

    float* ws  = (float*)d_ws;
    unsigned short* psb = (unsigned short*)ws;
    unsigned short* prb = (unsigned short*)(ws + 524288);
    unsigned short* w2b = (unsigned short*)(ws + 1048576);
    float* agg = ws + 1056768;
    unsigned short* o1b = (unsigned short*)(ws + 1318912);
    unsigned short* o2b = (unsigned short*)(ws + 1327104);
    unsigned short* o3b = (unsigned short*)(ws + 1359872);
    float* out = (float*)d_out;

    hipLaunchKernelGGL(prep_kernel, dim3(704), dim3(256), 0, stream,
                       x, W1, b1, W2, O1, O2, O3, psb, prb, w2b, o1b, o2b, o3b);
    hipLaunchKernelGGL(edge_kernel, dim3(2048), dim3(256), 0, stream,
                       rt, b2, psb, prb, w2b, agg);
    hipLaunchKernelGGL(node_kernel, dim3(256), dim3(256), 0, stream,
                       agg, o1b, b1o, o2b, b2o, o3b, b3o, out);
}